// Round 3
// baseline (519.346 us; speedup 1.0000x reference)
//
#include <hip/hip_runtime.h>
#include <cmath>

#define NN 8192
#define KK 64
#define DD 256
#define HH 128
#define SET0V 32
#define EE (NN*KK)

typedef float f4_t __attribute__((ext_vector_type(4)));

static constexpr size_t OFF_ADJ  = 0;
static constexpr size_t OFF_FEAT = (size_t)NN * NN;             // 67108864
static constexpr size_t OFF_PROB = OFF_FEAT + (size_t)NN * DD;  // 69206016
static constexpr size_t OFF_PAIR = OFF_PROB + (size_t)EE * 2;   // 70254592
static constexpr size_t OFF_BEF  = OFF_PAIR + (size_t)EE * 2;   // 71303168
static constexpr size_t OFF_AFT  = OFF_BEF + 1;                 // 71303169
static constexpr size_t OFF_LEFT = OFF_AFT + 1;                 // 71303170

// ---------------------------------------------------------------------------
// k_g: g = feat @ W1 in fp64 ([8192,256]x[256,128] -> [8192,128] doubles),
// feat copy-out, the two scalars, AND (new this round) the 256 MB zero-fill
// of out_adj. Rationale: k_g is fp64-compute-bound (~15 us, ~1.6 TB/s BW),
// so the streaming fill rides under idle store BW here instead of clogging
// k_main's VMEM queue (stores+loads share vmcnt/issue on gfx9, so the fill
// was serializing k_main's latency-critical g gathers).
// Block b zero-fills out_adj f4[b*16384 .. +16384) = 256 KB, 2 nt stores per
// thread per k-iteration (64 iters x 2 x 128 thr x 16B = 256 KB). Kernel
// boundary orders the fill before k_main's scatter into the same rows.
// Expected ~45-50 us (BW floor 272 MB writes / 6.4 TB/s).
// ---------------------------------------------------------------------------
__global__ __launch_bounds__(128) void k_g(const float* __restrict__ feat,
                                           const float* __restrict__ W1,
                                           double* __restrict__ g,
                                           f4_t* __restrict__ out_feat,
                                           float* __restrict__ out_scal,
                                           f4_t* __restrict__ out_adj4) {
  __shared__ float sf[8 * DD];  // 8 KiB
  int j = threadIdx.x;          // 0..127 = output col
  int n0 = blockIdx.x * 8;
  const f4_t* fsrc = (const f4_t*)(feat + (size_t)n0 * DD);
  f4_t* fdst = (f4_t*)sf;
  f4_t* odst = out_feat + (size_t)n0 * DD / 4;
#pragma unroll
  for (int t = 0; t < 4; t++) {
    f4_t v = fsrc[j + t * 128];
    fdst[j + t * 128] = v;
    __builtin_nontemporal_store(v, odst + j + t * 128);  // fused feat copy-out
  }
  if (blockIdx.x == 0 && j == 0) {
    out_scal[0] = 64.0f;  // before_edge_num
    out_scal[1] = 32.0f;  // after_edge_num (kept vals >= 0.1, never zero)
  }
  __syncthreads();
  f4_t* fill = out_adj4 + (size_t)blockIdx.x * 16384 + j;
  const f4_t z = {0.f, 0.f, 0.f, 0.f};
  double acc[8];
#pragma unroll
  for (int n = 0; n < 8; n++) acc[n] = 0.0;
  int it = 0;
  for (int k = 0; k < DD; k += 4) {
    // interleaved zero-fill of out_adj: 2 nt f4 stores per iteration
    __builtin_nontemporal_store(z, fill + (size_t)(2 * it) * 128);
    __builtin_nontemporal_store(z, fill + (size_t)(2 * it + 1) * 128);
    it++;
    double w0 = (double)W1[(k + 0) * HH + j];
    double w1 = (double)W1[(k + 1) * HH + j];
    double w2 = (double)W1[(k + 2) * HH + j];
    double w3 = (double)W1[(k + 3) * HH + j];
#pragma unroll
    for (int n = 0; n < 8; n++) {
      f4_t f = *(const f4_t*)&sf[n * DD + k];
      acc[n] += (double)f.x * w0;
      acc[n] += (double)f.y * w1;
      acc[n] += (double)f.z * w2;
      acc[n] += (double)f.w * w3;
    }
  }
#pragma unroll
  for (int n = 0; n < 8; n++) g[(size_t)(n0 + n) * HH + j] = acc[n];
}

// ---------------------------------------------------------------------------
// k_main: per-row MLP + rank + scatter. One wave per dst row (4 rows/block).
// CHANGED this round: the interleaved nt zero-fill moved to k_g, so the grp
// loop is pure gather+fp64-MLP (no streaming stores competing with the
// latency-critical g gathers for the VMEM queue/vmcnt), and the pre-scatter
// vmcnt(0) drain is gone (no in-kernel WAW anymore; the zeroed row comes
// from k_g, ordered by the kernel boundary).
// Kept from r2 (validated, neutral): wave-local lgkmcnt for the rank pass
// (no block barriers), fp64 shfl_xor butterfly for deg.
// Rank key stays fp64 end-to-end. absmax expected unchanged (~0.0039).
// ---------------------------------------------------------------------------
__global__ __launch_bounds__(256) void k_main(
    const double* __restrict__ g, const int* __restrict__ nbr,
    const float* __restrict__ b1, const float* __restrict__ b2,
    const float* __restrict__ pa, const float* __restrict__ W2,
    const float* __restrict__ adj, float* __restrict__ out_adj,
    float* __restrict__ out_prob, float* __restrict__ out_pair,
    float* __restrict__ out_left) {
  int wave = threadIdx.x >> 6;
  int lane = threadIdx.x & 63;
  int r = blockIdx.x * 4 + wave;
  int q = lane >> 4;   // edge slot 0..3
  int s = lane & 15;   // dim segment 0..15

  const int* nrow = nbr + r * KK;
  int c_mine = nrow[lane];                                   // early issue
  float v = __builtin_nontemporal_load(&adj[(size_t)r * NN + c_mine]);  // early

  double grb[8], aa[8], w0c[8], w1c[8];
  const double* gr = g + (size_t)r * HH + s * 8;
#pragma unroll
  for (int d = 0; d < 8; d++) {
    int dim = s * 8 + d;
    grb[d] = gr[d] + (double)b1[dim];
    aa[d]  = (double)pa[dim];
    w0c[d] = (double)W2[2 * dim];
    w1c[d] = (double)W2[2 * dim + 1];
  }

  double st0 = 0.0, st1 = 0.0;
  for (int grp = 0; grp < 16; grp++) {
    int c = nrow[grp * 4 + q];
    const double* gc = g + (size_t)c * HH + s * 8;
    double t0 = 0.0, t1 = 0.0;
#pragma unroll
    for (int d = 0; d < 8; d++) {
      double h = grb[d] - gc[d];
      h = h >= 0.0 ? h : aa[d] * h;
      t0 += h * w0c[d];
      t1 += h * w1c[d];
    }
#pragma unroll
    for (int m = 1; m < 16; m <<= 1) {
      t0 += __shfl_xor(t0, m, 16);
      t1 += __shfl_xor(t1, m, 16);
    }
    if (s == grp) { st0 = t0; st1 = t1; }  // lane q*16+grp keeps edge grp*4+q
  }
  int src = ((lane & 3) << 4) | (lane >> 2);
  double T0 = __shfl(st0, src, 64);
  double T1 = __shfl(st1, src, 64);
  double l0 = T0 + (double)b2[0];
  double l1 = T1 + (double)b2[1];
  double dkey = l1 - l0;               // rank key (monotone in p1)

  // prob / pair outputs (coalesced float2)
  size_t e = (size_t)r * KK + lane;
  float dm = (float)(l0 > l1 ? l0 : l1);
  float e0 = expf((float)l0 - dm), e1 = expf((float)l1 - dm);
  float inv = 1.0f / (e0 + e1);
  *(float2*)(out_prob + 2 * e) = make_float2(e0 * inv, e1 * inv);
  *(float2*)(out_pair + 2 * e) = make_float2((float)r, (float)c_mine);

  // stable ascending rank (ties by index = jnp stable argsort).
  // sp[] is private per wave -> intra-wave lgkmcnt wait, no block barrier.
  __shared__ double sp[4][64];
  sp[wave][lane] = dkey;
  asm volatile("s_waitcnt lgkmcnt(0)" ::: "memory");
  __builtin_amdgcn_sched_barrier(0);
  int rank = 0;
#pragma unroll 8
  for (int j = 0; j < KK; j++) {
    double qq = sp[wave][j];
    rank += (int)((qq < dkey) || (qq == dkey && j < lane));
  }
  bool kept = rank >= SET0V;

  // degree: fp64 xor-butterfly allreduce (identical result in all lanes)
  double dv = kept ? (double)v : 0.0;
#pragma unroll
  for (int m = 1; m < 64; m <<= 1) dv += __shfl_xor(dv, m, 64);

  if (kept) {
    out_adj[(size_t)r * NN + c_mine] = (float)((double)v / (dv + 1e-6));
    out_left[(size_t)r * SET0V + (rank - SET0V)] = (float)(r * KK + lane);
  }
}

extern "C" void kernel_launch(void* const* d_in, const int* in_sizes, int n_in,
                              void* d_out, int out_size, void* d_ws, size_t ws_size,
                              hipStream_t stream) {
  const float* adj  = (const float*)d_in[0];
  const float* feat = (const float*)d_in[1];
  const int*   nbr  = (const int*)d_in[2];
  const float* W1   = (const float*)d_in[4];
  const float* b1   = (const float*)d_in[5];
  const float* pa   = (const float*)d_in[6];
  const float* W2   = (const float*)d_in[7];
  const float* b2   = (const float*)d_in[8];
  float* out = (float*)d_out;

  double* g = (double*)d_ws;  // 8192*128 doubles = 8 MiB

  hipLaunchKernelGGL(k_g, dim3(1024), dim3(128), 0, stream,
                     feat, W1, g, (f4_t*)(out + OFF_FEAT), out + OFF_BEF,
                     (f4_t*)(out + OFF_ADJ));
  hipLaunchKernelGGL(k_main, dim3(2048), dim3(256), 0, stream,
                     g, nbr, b1, b2, pa, W2, adj,
                     out + OFF_ADJ, out + OFF_PROB, out + OFF_PAIR,
                     out + OFF_LEFT);
}

// Round 4
// 512.839 us; speedup vs baseline: 1.0127x; 1.0127x over previous
//
#include <hip/hip_runtime.h>
#include <cmath>

#define NN 8192
#define KK 64
#define DD 256
#define HH 128
#define SET0V 32
#define EE (NN*KK)

typedef float f4_t __attribute__((ext_vector_type(4)));

static constexpr size_t OFF_ADJ  = 0;
static constexpr size_t OFF_FEAT = (size_t)NN * NN;             // 67108864
static constexpr size_t OFF_PROB = OFF_FEAT + (size_t)NN * DD;  // 69206016
static constexpr size_t OFF_PAIR = OFF_PROB + (size_t)EE * 2;   // 70254592
static constexpr size_t OFF_BEF  = OFF_PAIR + (size_t)EE * 2;   // 71303168
static constexpr size_t OFF_AFT  = OFF_BEF + 1;                 // 71303169
static constexpr size_t OFF_LEFT = OFF_AFT + 1;                 // 71303170

// ---------------------------------------------------------------------------
// k_g: g = feat @ W1 in fp64 ([8192,256]x[256,128] -> [8192,128] doubles),
// plus feat copy-out (non-temporal) and the two scalar outputs.
// Reverted to the r2 form: NO out_adj fill here (r3 showed the fill
// serializes at BW in this short kernel, +40us; it must hide under k_main).
// ---------------------------------------------------------------------------
__global__ __launch_bounds__(128) void k_g(const float* __restrict__ feat,
                                           const float* __restrict__ W1,
                                           double* __restrict__ g,
                                           f4_t* __restrict__ out_feat,
                                           float* __restrict__ out_scal) {
  __shared__ float sf[8 * DD];  // 8 KiB
  int j = threadIdx.x;          // 0..127 = output col
  int n0 = blockIdx.x * 8;
  const f4_t* fsrc = (const f4_t*)(feat + (size_t)n0 * DD);
  f4_t* fdst = (f4_t*)sf;
  f4_t* odst = out_feat + (size_t)n0 * DD / 4;
#pragma unroll
  for (int t = 0; t < 4; t++) {
    f4_t v = fsrc[j + t * 128];
    fdst[j + t * 128] = v;
    __builtin_nontemporal_store(v, odst + j + t * 128);  // fused feat copy-out
  }
  if (blockIdx.x == 0 && j == 0) {
    out_scal[0] = 64.0f;  // before_edge_num
    out_scal[1] = 32.0f;  // after_edge_num (kept vals >= 0.1, never zero)
  }
  __syncthreads();
  double acc[8];
#pragma unroll
  for (int n = 0; n < 8; n++) acc[n] = 0.0;
  for (int k = 0; k < DD; k += 4) {
    double w0 = (double)W1[(k + 0) * HH + j];
    double w1 = (double)W1[(k + 1) * HH + j];
    double w2 = (double)W1[(k + 2) * HH + j];
    double w3 = (double)W1[(k + 3) * HH + j];
#pragma unroll
    for (int n = 0; n < 8; n++) {
      f4_t f = *(const f4_t*)&sf[n * DD + k];
      acc[n] += (double)f.x * w0;
      acc[n] += (double)f.y * w1;
      acc[n] += (double)f.z * w2;
      acc[n] += (double)f.w * w3;
    }
  }
#pragma unroll
  for (int n = 0; n < 8; n++) g[(size_t)(n0 + n) * HH + j] = acc[n];
}

// ---------------------------------------------------------------------------
// k_main, restructured: TWO waves cooperate on one dst row (2 rows per
// 256-thread block, grid 4096). Wave half w computes edge-groups for edges
// 32w..32w+31, HALVING the serial gather->MLP->butterfly chain (16 -> 8
// dependent iterations) that rounds 0-3 identified as the only untested
// limiter. Results cross the wave pair via an LDS transpose (sdk/sl0/sl1),
// which the rank pass needed anyway.
// Fill placement = best of r2/r3: the gather loop is store-free (r3's -18us
// lesson), the 16 nt zero-stores per lane issue AFTER the loop and drain at
// the block barrier, overlapping the rank/deg LDS phase -- and the barrier's
// implicit vmcnt(0) provides the cross-wave WAW ordering the scatter needs
// (kept columns land anywhere in the row, including the other wave's fill
// half).
// dkey fp64 path is bit-identical to r0-r2 (same s-partition, same butterfly
// tree, same b2 add) -> identical ranks/ties. absmax expected 0.0039.
// ---------------------------------------------------------------------------
__global__ __launch_bounds__(256) void k_main(
    const double* __restrict__ g, const int* __restrict__ nbr,
    const float* __restrict__ b1, const float* __restrict__ b2,
    const float* __restrict__ pa, const float* __restrict__ W2,
    const float* __restrict__ adj, float* __restrict__ out_adj,
    float* __restrict__ out_prob, float* __restrict__ out_pair,
    float* __restrict__ out_left) {
  int wave = threadIdx.x >> 6;
  int lane = threadIdx.x & 63;
  int half = wave & 1;   // which 32-edge half this wave computes
  int rloc = wave >> 1;  // 0..1 row within block
  int r = blockIdx.x * 2 + rloc;
  int q = lane >> 4;     // edge slot 0..3 within group
  int s = lane & 15;     // dim segment 0..15

  const int* nrow = nbr + r * KK;
  int e_mine = 32 * half + (lane & 31);  // edge this lane owns in phase 2
  int c_mine = nrow[e_mine];             // early issue
  float v = __builtin_nontemporal_load(&adj[(size_t)r * NN + c_mine]);  // early

  double grb[8], aa[8], w0c[8], w1c[8];
  const double* gr = g + (size_t)r * HH + s * 8;
#pragma unroll
  for (int d = 0; d < 8; d++) {
    int dim = s * 8 + d;
    grb[d] = gr[d] + (double)b1[dim];
    aa[d]  = (double)pa[dim];
    w0c[d] = (double)W2[2 * dim];
    w1c[d] = (double)W2[2 * dim + 1];
  }

  // phase 1: 8 dependent gather->MLP->butterfly groups (was 16)
  double st0 = 0.0, st1 = 0.0;
  for (int grp = 0; grp < 8; grp++) {
    int c = nrow[32 * half + grp * 4 + q];
    const double* gc = g + (size_t)c * HH + s * 8;
    double t0 = 0.0, t1 = 0.0;
#pragma unroll
    for (int d = 0; d < 8; d++) {
      double h = grb[d] - gc[d];
      h = h >= 0.0 ? h : aa[d] * h;
      t0 += h * w0c[d];
      t1 += h * w1c[d];
    }
#pragma unroll
    for (int m = 1; m < 16; m <<= 1) {
      t0 += __shfl_xor(t0, m, 16);
      t1 += __shfl_xor(t1, m, 16);
    }
    if (s == grp) { st0 = t0; st1 = t1; }  // lane (q,s) keeps edge 32w+4s+q
  }
  double l0 = st0 + (double)b2[0];   // valid where s < 8
  double l1 = st1 + (double)b2[1];
  double dk = l1 - l0;

  __shared__ double sl0[2][64], sl1[2][64], sdk[2][64], sv[2][64];
  if (s < 8) {
    int el = 32 * half + 4 * s + q;
    sl0[rloc][el] = l0;
    sl1[rloc][el] = l1;
    sdk[rloc][el] = dk;
  }

  // post-loop zero-fill: 16 nt f4 stores per lane (this wave's row half);
  // issues here, drains at the barrier below while LDS phase proceeds
  f4_t* row4 = (f4_t*)(out_adj + (size_t)r * NN) + half * 1024 + lane;
  const f4_t z = {0.f, 0.f, 0.f, 0.f};
#pragma unroll
  for (int t = 0; t < 16; t++)
    __builtin_nontemporal_store(z, row4 + t * 64);

  __syncthreads();  // vmcnt(0)+lgkmcnt(0)+s_barrier: fills done, LDS visible

  // phase 2: lanes 0..31 of each wave own edges e_mine (lanes 32..63 shadow)
  double L0 = sl0[rloc][e_mine];
  double L1 = sl1[rloc][e_mine];
  double dkey = sdk[rloc][e_mine];

  if (lane < 32) {
    size_t e = (size_t)r * KK + e_mine;
    float dm = (float)(L0 > L1 ? L0 : L1);
    float e0 = expf((float)L0 - dm), e1 = expf((float)L1 - dm);
    float inv = 1.0f / (e0 + e1);
    *(float2*)(out_prob + 2 * e) = make_float2(e0 * inv, e1 * inv);
    *(float2*)(out_pair + 2 * e) = make_float2((float)r, (float)c_mine);
  }

  // stable ascending rank (ties by index = jnp stable argsort)
  int rank = 0;
#pragma unroll 8
  for (int j = 0; j < KK; j++) {
    double qq = sdk[rloc][j];  // broadcast read
    rank += (int)((qq < dkey) || (qq == dkey && j < e_mine));
  }
  bool kept = rank >= SET0V;

  if (lane < 32) sv[rloc][e_mine] = kept ? (double)v : 0.0;
  __syncthreads();
  double deg = 0.0;
#pragma unroll 8
  for (int j = 0; j < KK; j++) deg += sv[rloc][j];  // broadcast reads

  if (lane < 32 && kept) {
    out_adj[(size_t)r * NN + c_mine] = (float)((double)v / (deg + 1e-6));
    out_left[(size_t)r * SET0V + (rank - SET0V)] = (float)(r * KK + e_mine);
  }
}

extern "C" void kernel_launch(void* const* d_in, const int* in_sizes, int n_in,
                              void* d_out, int out_size, void* d_ws, size_t ws_size,
                              hipStream_t stream) {
  const float* adj  = (const float*)d_in[0];
  const float* feat = (const float*)d_in[1];
  const int*   nbr  = (const int*)d_in[2];
  const float* W1   = (const float*)d_in[4];
  const float* b1   = (const float*)d_in[5];
  const float* pa   = (const float*)d_in[6];
  const float* W2   = (const float*)d_in[7];
  const float* b2   = (const float*)d_in[8];
  float* out = (float*)d_out;

  double* g = (double*)d_ws;  // 8192*128 doubles = 8 MiB

  hipLaunchKernelGGL(k_g, dim3(1024), dim3(128), 0, stream,
                     feat, W1, g, (f4_t*)(out + OFF_FEAT), out + OFF_BEF);
  hipLaunchKernelGGL(k_main, dim3(4096), dim3(256), 0, stream,
                     g, nbr, b1, b2, pa, W2, adj,
                     out + OFF_ADJ, out + OFF_PROB, out + OFF_PAIR,
                     out + OFF_LEFT);
}